// Round 7
// baseline (701.848 us; speedup 1.0000x reference)
//
#include <hip/hip_runtime.h>
#include <cstdint>
#include <cstddef>

// Problem constants
#define B_ 8
#define NT 1024
#define NK 1024
#define D_ 768
#define H_ 8
#define HD_ 96
#define CLS_ 20
#define L_ 1044
#define SCALE_ 0.10206207261596577f
#define TQ 8
// integer mask threshold: bits < THR  <=>  uniform(bits) < 0.3f (exact)
#define MASK_THR 1288490496u

typedef __attribute__((ext_vector_type(8))) short bf16x8;
typedef __attribute__((ext_vector_type(4))) float f32x4;

__device__ __forceinline__ unsigned short f2bf(float f) {
    uint32_t u = __float_as_uint(f);
    u += 0x7FFFu + ((u >> 16) & 1u);   // RNE (no NaN inputs here)
    return (unsigned short)(u >> 16);
}

// async global->LDS, 16B per lane; LDS dest = wave-uniform base + lane*16
__device__ __forceinline__ void gll16(const void* g, void* l) {
    __builtin_amdgcn_global_load_lds(
        (const __attribute__((address_space(1))) unsigned int*)g,
        (__attribute__((address_space(3))) unsigned int*)l,
        16, 0, 0);
}

// ---------------------------------------------------------------------------
// JAX threefry2x32, partitionable scheme (verified round 3):
// counter = (0, g), output bits = x0 ^ x1. key = (0, 42).
// ---------------------------------------------------------------------------
__device__ __forceinline__ uint32_t tf_bits(uint32_t g) {
    const uint32_t k0 = 0u, k1 = 42u;
    const uint32_t ks2 = k0 ^ k1 ^ 0x1BD11BDAu;
    uint32_t x0 = 0u, x1 = g;

    x0 += k0; x1 += k1;
#define TF_ROUND(r) { x0 += x1; x1 = (x1 << (r)) | (x1 >> (32 - (r))); x1 ^= x0; }
    TF_ROUND(13) TF_ROUND(15) TF_ROUND(26) TF_ROUND(6)
    x0 += k1;  x1 += ks2 + 1u;
    TF_ROUND(17) TF_ROUND(29) TF_ROUND(16) TF_ROUND(24)
    x0 += ks2; x1 += k0 + 2u;
    TF_ROUND(13) TF_ROUND(15) TF_ROUND(26) TF_ROUND(6)
    x0 += k0;  x1 += k1 + 3u;
    TF_ROUND(17) TF_ROUND(29) TF_ROUND(16) TF_ROUND(24)
    x0 += k1;  x1 += ks2 + 4u;
    TF_ROUND(13) TF_ROUND(15) TF_ROUND(26) TF_ROUND(6)
    x0 += ks2; x1 += k0 + 5u;
#undef TF_ROUND
    return x0 ^ x1;
}

// ---------------------------------------------------------------------------
// mask kernel: one u32 bitmask per (row, s): bit j = col (s+32j) masked.
// rows are the 8*8*1024 KEPT query rows (threefry row index = bh*1044+lq+20).
// Dense int-ALU, no LDS -> full occupancy.
// ---------------------------------------------------------------------------
__global__ __launch_bounds__(256) void mask_kernel(uint32_t* __restrict__ mb)
{
    const int t  = blockIdx.x * 256 + threadIdx.x;   // 0 .. 2097151
    const int s  = t & 31;
    const int lq = (t >> 5) & 1023;
    const int bh = t >> 15;                          // b*8+h
    const uint32_t row = (uint32_t)bh * (uint32_t)L_ + (uint32_t)lq + (uint32_t)CLS_;
    const uint32_t g0  = row * 1024u + (uint32_t)s;
    uint32_t m = 0u;
#pragma unroll 4
    for (int j = 0; j < 32; ++j) {
        uint32_t bits = tf_bits(g0 + 32u * (uint32_t)j);
        m |= (bits < MASK_THR ? 1u : 0u) << j;
    }
    mb[t] = m;
}

// ---------------------------------------------------------------------------
// fp32 -> bf16 flat convert (float4 granular)
// ---------------------------------------------------------------------------
__global__ __launch_bounds__(256) void conv_bf16(
    const float* __restrict__ src, unsigned short* __restrict__ dst, int n4)
{
    int i = blockIdx.x * 256 + threadIdx.x;
    if (i < n4) {
        float4 v = ((const float4*)src)[i];
        ushort4 o;
        o.x = f2bf(v.x); o.y = f2bf(v.y); o.z = f2bf(v.z); o.w = f2bf(v.w);
        ((ushort4*)dst)[i] = o;
    }
}

// ---------------------------------------------------------------------------
// weight transpose: W[768][Nn] fp32 -> Wt[Nn][768] bf16, 32x32 tiles
// ---------------------------------------------------------------------------
__global__ __launch_bounds__(256) void trw_bf16(
    const float* __restrict__ W, unsigned short* __restrict__ Wt, int Nn)
{
    __shared__ unsigned short tile[32][36];
    const int n0 = blockIdx.x * 32, k0 = blockIdx.y * 32;
    const int t = threadIdx.x, r = t >> 3, c4 = (t & 7) * 4;

    float4 v = *(const float4*)&W[(size_t)(k0 + r) * Nn + n0 + c4];
    tile[r][c4 + 0] = f2bf(v.x);
    tile[r][c4 + 1] = f2bf(v.y);
    tile[r][c4 + 2] = f2bf(v.z);
    tile[r][c4 + 3] = f2bf(v.w);
    __syncthreads();

    ushort4 o;
    o.x = tile[c4 + 0][r];
    o.y = tile[c4 + 1][r];
    o.z = tile[c4 + 2][r];
    o.w = tile[c4 + 3][r];
    *(ushort4*)&Wt[(size_t)(n0 + r) * 768 + k0 + c4] = o;
}

// ---------------------------------------------------------------------------
// V transpose: kv16[8192][1536] bf16 (V half at col 768+h*96) ->
//              vT[(b*8+h)*96 + d][1024] bf16
// ---------------------------------------------------------------------------
__global__ __launch_bounds__(256) void trv(
    const unsigned short* __restrict__ kv16, unsigned short* __restrict__ vT)
{
    const int bid = blockIdx.x;       // (b*8+h)*16 + nt
    const int nt = bid & 15, bh = bid >> 4;
    const int b = bh >> 3, h = bh & 7;
    const int n0 = nt * 64;
    const int t = threadIdx.x;

    __shared__ unsigned short tile[64][104];

    for (int i = t; i < 768; i += 256) {
        int r = i / 12, c = i % 12;
        *(uint4*)&tile[r][c * 8] =
            *(const uint4*)&kv16[(size_t)(b * 1024 + n0 + r) * 1536 + 768 + h * 96 + c * 8];
    }
    __syncthreads();

    for (int i = t; i < 768; i += 256) {
        int d = i >> 3, c = i & 7;
        ushort4 lo, hi;
        lo.x = tile[c * 8 + 0][d]; lo.y = tile[c * 8 + 1][d];
        lo.z = tile[c * 8 + 2][d]; lo.w = tile[c * 8 + 3][d];
        hi.x = tile[c * 8 + 4][d]; hi.y = tile[c * 8 + 5][d];
        hi.z = tile[c * 8 + 6][d]; hi.w = tile[c * 8 + 7][d];
        const size_t ob = ((size_t)bh * 96 + d) * 1024 + n0 + c * 8;
        *(ushort4*)&vT[ob]     = lo;
        *(ushort4*)&vT[ob + 4] = hi;
    }
}

// ---------------------------------------------------------------------------
// bf16 MFMA GEMM, NT form: C[M,N] = A[M,K] @ Bt[N,K]^T. (round-6, unchanged)
// MODE 0: bf16 out. MODE 1: fp32 out + bias, split-A (A + Alo).
// ---------------------------------------------------------------------------
template <int MODE>
__global__ __launch_bounds__(256) void mfma_gemm(
    const unsigned short* __restrict__ A,
    const unsigned short* __restrict__ Alo,
    const unsigned short* __restrict__ Bt,
    const float* __restrict__ bias,
    unsigned short* __restrict__ Cb, float* __restrict__ Cf,
    int N, int K)
{
    __shared__ unsigned short As[128 * 32];
    __shared__ unsigned short Bs[128 * 32];
    __shared__ unsigned short Als[MODE == 1 ? 128 * 32 : 8];

    const int tid  = threadIdx.x;
    const int lane = tid & 63, wv = tid >> 6;
    const int bm = blockIdx.y * 128, bn = blockIdx.x * 128;
    const int mcol = lane & 15, quad = lane >> 4;
    const int wr = (wv & 1) * 64, wc = (wv >> 1) * 64;
    const int srow = lane >> 2;
    const int skch = (lane & 3) * 8;

    f32x4 acc[4][4];
#pragma unroll
    for (int i = 0; i < 4; ++i)
#pragma unroll
        for (int j = 0; j < 4; ++j) acc[i][j] = (f32x4){0.f, 0.f, 0.f, 0.f};

    for (int k0 = 0; k0 < K; k0 += 32) {
#pragma unroll
        for (int c = 0; c < 2; ++c) {
            const int s = wv * 2 + c;
            const int row = s * 16 + srow;
            gll16(&A [(size_t)(bm + row) * K + k0 + skch], &As[s * 512]);
            gll16(&Bt[(size_t)(bn + row) * K + k0 + skch], &Bs[s * 512]);
            if (MODE == 1)
                gll16(&Alo[(size_t)(bm + row) * K + k0 + skch], &Als[s * 512]);
        }
        __syncthreads();

        bf16x8 af[4], bfr[4], al[4];
#pragma unroll
        for (int i = 0; i < 4; ++i) {
            af[i]  = *(const bf16x8*)&As[(wr + i * 16 + mcol) * 32 + quad * 8];
            bfr[i] = *(const bf16x8*)&Bs[(wc + i * 16 + mcol) * 32 + quad * 8];
            if (MODE == 1)
                al[i] = *(const bf16x8*)&Als[(wr + i * 16 + mcol) * 32 + quad * 8];
        }
#pragma unroll
        for (int i = 0; i < 4; ++i)
#pragma unroll
            for (int j = 0; j < 4; ++j) {
                acc[i][j] = __builtin_amdgcn_mfma_f32_16x16x32_bf16(af[i], bfr[j], acc[i][j], 0, 0, 0);
                if (MODE == 1)
                    acc[i][j] = __builtin_amdgcn_mfma_f32_16x16x32_bf16(al[i], bfr[j], acc[i][j], 0, 0, 0);
            }
        __syncthreads();
    }

#pragma unroll
    for (int j = 0; j < 4; ++j) {
        const int col = bn + wc + j * 16 + mcol;
        float bs = 0.f;
        if (MODE == 1) bs = bias[col];
#pragma unroll
        for (int i = 0; i < 4; ++i)
#pragma unroll
            for (int rg = 0; rg < 4; ++rg) {
                const int rrow = bm + wr + i * 16 + quad * 4 + rg;
                if (MODE == 0) Cb[(size_t)rrow * N + col] = f2bf(acc[i][j][rg]);
                else           Cf[(size_t)rrow * N + col] = acc[i][j][rg] + bs;
            }
    }
}

// ---------------------------------------------------------------------------
// Attention v4: register-resident softmax. One block per (b,h,8-row tile).
// QK MFMA -> sP (fp32 logits) -> gather 32 cols/thread into VGPRs ->
// all softmax passes in regs (shfl reductions, no rstat ping-pong) ->
// bf16 exp into sPb (ALIASES sP storage; LDS total 32.8 KB -> 4 blk/CU) ->
// PV MFMA. Mask from precomputed bitmask buffer.
// ---------------------------------------------------------------------------
__global__ __launch_bounds__(256, 4) void attn_kernel(
    const unsigned short* __restrict__ qb, const unsigned short* __restrict__ kv16,
    const unsigned short* __restrict__ vT, const uint32_t* __restrict__ mb,
    unsigned short* __restrict__ xh, unsigned short* __restrict__ xl)
{
    const int bid  = blockIdx.x;       // b*8*128 + h*128 + tile
    const int tile = bid & 127;
    const int h    = (bid >> 7) & 7;
    const int b    = bid >> 10;
    const int lq0  = tile * TQ;
    const int tid  = threadIdx.x;
    const int lane = tid & 63;
    const int wv   = tid >> 6;
    const int mcol = lane & 15;
    const int quad = lane >> 4;

    __shared__ __align__(16) float sP[TQ][1024];   // logits; later aliased as bf16 probs
    __shared__ float rs2[TQ];
    unsigned short* sPb = (unsigned short*)&sP[0][0];   // [TQ][1032] stride, 16.5 KB < 32 KB

    // ---- QK^T via MFMA (round-6 structure) ----
    {
        const size_t qrow = ((size_t)(b * NT) + lq0 + (mcol & 7)) * 768 + h * 96 + quad * 8;
        const bf16x8 qa0 = *(const bf16x8*)&qb[qrow];
        const bf16x8 qa1 = *(const bf16x8*)&qb[qrow + 32];
        const bf16x8 qa2 = *(const bf16x8*)&qb[qrow + 64];

        for (int nt = wv * 16; nt < wv * 16 + 16; ++nt) {
            const int n0 = nt * 16;
            const size_t krow = ((size_t)(b * NK) + n0 + mcol) * 1536 + h * 96 + quad * 8;
            f32x4 d = {0.f, 0.f, 0.f, 0.f};
            d = __builtin_amdgcn_mfma_f32_16x16x32_bf16(qa0, *(const bf16x8*)&kv16[krow],      d, 0, 0, 0);
            d = __builtin_amdgcn_mfma_f32_16x16x32_bf16(qa1, *(const bf16x8*)&kv16[krow + 32], d, 0, 0, 0);
            d = __builtin_amdgcn_mfma_f32_16x16x32_bf16(qa2, *(const bf16x8*)&kv16[krow + 64], d, 0, 0, 0);
            if (quad < 2) {
#pragma unroll
                for (int rg = 0; rg < 4; ++rg)
                    sP[quad * 4 + rg][n0 + mcol] = d[rg] * SCALE_;
            }
        }
    }
    __syncthreads();

    // ---- gather this thread's 32 columns into registers ----
    const int r = tid >> 5, s = tid & 31;   // row r, lane s within 32-group
    float v[32];
#pragma unroll
    for (int j = 0; j < 32; ++j) v[j] = sP[r][s + 32 * j];
    __syncthreads();   // sP storage now free for sPb overwrite

    // ---- patch max (cols >= 20): j>=1 always patch; j==0 col=s is cls iff s<20
    float mx = -INFINITY;
#pragma unroll
    for (int j = 1; j < 32; ++j) mx = fmaxf(mx, v[j]);
    if (s >= CLS_) mx = fmaxf(mx, v[0]);
#pragma unroll
    for (int m = 1; m <= 16; m <<= 1) mx = fmaxf(mx, __shfl_xor(mx, m));
    const float pm = mx;

    // ---- cls stats over lanes s<20 (parallel, replaces serial loop) ----
    float cv = (s < CLS_) ? v[0] : -INFINITY;
#pragma unroll
    for (int m = 1; m <= 16; m <<= 1) cv = fmaxf(cv, __shfl_xor(cv, m));
    const float cm = cv;
    float ce = (s < CLS_) ? __expf(v[0] - cm) : 0.f;
#pragma unroll
    for (int m = 1; m <= 16; m <<= 1) ce += __shfl_xor(ce, m);
    const float ics = 1.f / ce;

    // ---- single exp pass: e stored in regs, patch sum accumulated ----
    float ps = 0.f;
    {
        const float sub0 = (s < CLS_) ? cm : pm;
        float e0 = __expf(v[0] - sub0);
        if (s >= CLS_) ps += e0;
        v[0] = e0;
    }
#pragma unroll
    for (int j = 1; j < 32; ++j) { float e = __expf(v[j] - pm); ps += e; v[j] = e; }
#pragma unroll
    for (int m = 1; m <= 16; m <<= 1) ps += __shfl_xor(ps, m);
    const float ips = 1.f / ps;

    // ---- probs + mask (masked -> -1e30; exp later underflows to exact 0) ----
    const uint32_t m32 = mb[(((uint32_t)(b * 8 + h) * 1024u + (uint32_t)(lq0 + r)) << 5) + (uint32_t)s];
    {
        float p0 = v[0] * ((s < CLS_) ? ics : ips);
        v[0] = (m32 & 1u) ? -1e30f : p0;
    }
#pragma unroll
    for (int j = 1; j < 32; ++j) {
        float p = v[j] * ips;
        v[j] = ((m32 >> j) & 1u) ? -1e30f : p;
    }

    // ---- second softmax: max, exp (unnormalized, bf16), sum ----
    float mx2 = v[0];
#pragma unroll
    for (int j = 1; j < 32; ++j) mx2 = fmaxf(mx2, v[j]);
#pragma unroll
    for (int m = 1; m <= 16; m <<= 1) mx2 = fmaxf(mx2, __shfl_xor(mx2, m));
    const float m2 = mx2;

    float s2 = 0.f;
#pragma unroll
    for (int j = 0; j < 32; ++j) {
        float e2 = __expf(v[j] - m2);   // masked: exp(-1e30-m2) = 0 exactly
        s2 += e2;
        sPb[r * 1032 + s + 32 * j] = f2bf(e2);
    }
#pragma unroll
    for (int m = 1; m <= 16; m <<= 1) s2 += __shfl_xor(s2, m);
    if (s == 0) rs2[r] = s2;
    __syncthreads();

    // ---- PV via MFMA (round-6 structure; sPb now flat-pointer) ----
    {
        const int t0 = wv, t1 = wv + 4;
        const size_t vbase = ((size_t)(b * 8 + h)) * 96 * 1024;
        f32x4 a0 = {0.f, 0.f, 0.f, 0.f};
        f32x4 a1 = {0.f, 0.f, 0.f, 0.f};
        for (int k0 = 0; k0 < 1024; k0 += 32) {
            const bf16x8 pa = *(const bf16x8*)&sPb[(mcol & 7) * 1032 + k0 + quad * 8];
            const size_t v0 = vbase + (size_t)(t0 * 16 + mcol) * 1024 + k0 + quad * 8;
            a0 = __builtin_amdgcn_mfma_f32_16x16x32_bf16(pa, *(const bf16x8*)&vT[v0], a0, 0, 0, 0);
            if (t1 < 6) {
                const size_t v1 = vbase + (size_t)(t1 * 16 + mcol) * 1024 + k0 + quad * 8;
                a1 = __builtin_amdgcn_mfma_f32_16x16x32_bf16(pa, *(const bf16x8*)&vT[v1], a1, 0, 0, 0);
            }
        }
        if (quad < 2) {
#pragma unroll
            for (int rg = 0; rg < 4; ++rg) {
                const int rw = quad * 4 + rg;
                const float inv = 1.f / rs2[rw];
                const size_t ob = ((size_t)(b * NT) + lq0 + rw) * 768 + h * 96;
                {
                    float val = a0[rg] * inv;
                    unsigned short hb = f2bf(val);
                    xh[ob + t0 * 16 + mcol] = hb;
                    xl[ob + t0 * 16 + mcol] = f2bf(val - __uint_as_float((uint32_t)hb << 16));
                }
                if (t1 < 6) {
                    float val = a1[rg] * inv;
                    unsigned short hb = f2bf(val);
                    xh[ob + t1 * 16 + mcol] = hb;
                    xl[ob + t1 * 16 + mcol] = f2bf(val - __uint_as_float((uint32_t)hb << 16));
                }
            }
        }
    }
}

// ---------------------------------------------------------------------------
extern "C" void kernel_launch(void* const* d_in, const int* in_sizes, int n_in,
                              void* d_out, int out_size, void* d_ws, size_t ws_size,
                              hipStream_t stream)
{
    const float* in_q   = (const float*)d_in[0];
    const float* in_k   = (const float*)d_in[1];
    const float* Wq     = (const float*)d_in[2];
    const float* Wkv    = (const float*)d_in[3];
    // d_in[4] = Wcls — unused (cls query rows are dropped by the reference)
    const float* Wproj  = (const float*)d_in[5];
    const float* bproj  = (const float*)d_in[6];
    float* out = (float*)d_out;

    // workspace layout (bf16 units); total 88.6 MB (<= 100.7 MB proven in r3)
    unsigned short* ws16 = (unsigned short*)d_ws;
    unsigned short* Aq   = ws16;                  // 6291456
    unsigned short* Ak   = Aq   + 6291456;        // 6291456
    unsigned short* qb   = Ak   + 6291456;        // 6291456
    unsigned short* kv16 = qb   + 6291456;        // 12582912
    unsigned short* vT   = kv16 + 12582912;       // 6291456
    unsigned short* Wqt  = vT   + 6291456;        // 589824
    unsigned short* Wkvt = Wqt  + 589824;         // 1179648
    unsigned short* Wpt  = Wkvt + 1179648;        // 589824
    uint32_t*       mb   = (uint32_t*)(Wpt + 589824);   // 2097152 u32
    unsigned short* xh   = Aq;                    // reuse (dead after gemm_q)
    unsigned short* xl   = Ak;                    // reuse (dead after gemm_kv)

    dim3 blk(256);

    mask_kernel<<<8192, blk, 0, stream>>>(mb);

    conv_bf16<<<6144, blk, 0, stream>>>(in_q, Aq, 1572864);
    conv_bf16<<<6144, blk, 0, stream>>>(in_k, Ak, 1572864);
    trw_bf16<<<dim3(24, 24), blk, 0, stream>>>(Wq,    Wqt,  768);
    trw_bf16<<<dim3(48, 24), blk, 0, stream>>>(Wkv,   Wkvt, 1536);
    trw_bf16<<<dim3(24, 24), blk, 0, stream>>>(Wproj, Wpt,  768);

    mfma_gemm<0><<<dim3(6, 64), blk, 0, stream>>>(
        Aq, nullptr, Wqt, nullptr, qb, nullptr, 768, 768);

    mfma_gemm<0><<<dim3(12, 64), blk, 0, stream>>>(
        Ak, nullptr, Wkvt, nullptr, kv16, nullptr, 1536, 768);

    trv<<<1024, blk, 0, stream>>>(kv16, vT);

    attn_kernel<<<8192, blk, 0, stream>>>(qb, kv16, vT, mb, xh, xl);

    mfma_gemm<1><<<dim3(6, 64), blk, 0, stream>>>(
        xh, xl, Wpt, bproj, nullptr, out, 768, 768);
}

// Round 8
// 440.062 us; speedup vs baseline: 1.5949x; 1.5949x over previous
//
#include <hip/hip_runtime.h>
#include <cstdint>
#include <cstddef>

// Problem constants
#define B_ 8
#define NT 1024
#define NK 1024
#define D_ 768
#define H_ 8
#define HD_ 96
#define CLS_ 20
#define L_ 1044
#define SCALE_ 0.10206207261596577f
#define TQ 16
// integer mask threshold: bits < THR  <=>  uniform(bits) < 0.3f (exact)
#define MASK_THR 1288490496u

typedef __attribute__((ext_vector_type(8))) short bf16x8;
typedef __attribute__((ext_vector_type(4))) float f32x4;

__device__ __forceinline__ unsigned short f2bf(float f) {
    uint32_t u = __float_as_uint(f);
    u += 0x7FFFu + ((u >> 16) & 1u);   // RNE (no NaN inputs here)
    return (unsigned short)(u >> 16);
}

// async global->LDS, 16B per lane; LDS dest = wave-uniform base + lane*16
__device__ __forceinline__ void gll16(const void* g, void* l) {
    __builtin_amdgcn_global_load_lds(
        (const __attribute__((address_space(1))) unsigned int*)g,
        (__attribute__((address_space(3))) unsigned int*)l,
        16, 0, 0);
}

// ---------------------------------------------------------------------------
// JAX threefry2x32, partitionable scheme (verified round 3):
// counter = (0, g), output bits = x0 ^ x1. key = (0, 42).
// ---------------------------------------------------------------------------
__device__ __forceinline__ uint32_t tf_bits(uint32_t g) {
    const uint32_t k0 = 0u, k1 = 42u;
    const uint32_t ks2 = k0 ^ k1 ^ 0x1BD11BDAu;
    uint32_t x0 = 0u, x1 = g;

    x0 += k0; x1 += k1;
#define TF_ROUND(r) { x0 += x1; x1 = (x1 << (r)) | (x1 >> (32 - (r))); x1 ^= x0; }
    TF_ROUND(13) TF_ROUND(15) TF_ROUND(26) TF_ROUND(6)
    x0 += k1;  x1 += ks2 + 1u;
    TF_ROUND(17) TF_ROUND(29) TF_ROUND(16) TF_ROUND(24)
    x0 += ks2; x1 += k0 + 2u;
    TF_ROUND(13) TF_ROUND(15) TF_ROUND(26) TF_ROUND(6)
    x0 += k0;  x1 += k1 + 3u;
    TF_ROUND(17) TF_ROUND(29) TF_ROUND(16) TF_ROUND(24)
    x0 += k1;  x1 += ks2 + 4u;
    TF_ROUND(13) TF_ROUND(15) TF_ROUND(26) TF_ROUND(6)
    x0 += ks2; x1 += k0 + 5u;
#undef TF_ROUND
    return x0 ^ x1;
}

// ---------------------------------------------------------------------------
// fp32 -> bf16 flat convert (float4 granular)
// ---------------------------------------------------------------------------
__global__ __launch_bounds__(256) void conv_bf16(
    const float* __restrict__ src, unsigned short* __restrict__ dst, int n4)
{
    int i = blockIdx.x * 256 + threadIdx.x;
    if (i < n4) {
        float4 v = ((const float4*)src)[i];
        ushort4 o;
        o.x = f2bf(v.x); o.y = f2bf(v.y); o.z = f2bf(v.z); o.w = f2bf(v.w);
        ((ushort4*)dst)[i] = o;
    }
}

// ---------------------------------------------------------------------------
// weight transpose: W[768][Nn] fp32 -> Wt[Nn][768] bf16 (* scale), 32x32 tiles
// ---------------------------------------------------------------------------
__global__ __launch_bounds__(256) void trw_bf16(
    const float* __restrict__ W, unsigned short* __restrict__ Wt, int Nn,
    float scale)
{
    __shared__ unsigned short tile[32][36];
    const int n0 = blockIdx.x * 32, k0 = blockIdx.y * 32;
    const int t = threadIdx.x, r = t >> 3, c4 = (t & 7) * 4;

    float4 v = *(const float4*)&W[(size_t)(k0 + r) * Nn + n0 + c4];
    tile[r][c4 + 0] = f2bf(v.x * scale);
    tile[r][c4 + 1] = f2bf(v.y * scale);
    tile[r][c4 + 2] = f2bf(v.z * scale);
    tile[r][c4 + 3] = f2bf(v.w * scale);
    __syncthreads();

    ushort4 o;
    o.x = tile[c4 + 0][r];
    o.y = tile[c4 + 1][r];
    o.z = tile[c4 + 2][r];
    o.w = tile[c4 + 3][r];
    *(ushort4*)&Wt[(size_t)(n0 + r) * 768 + k0 + c4] = o;
}

// ---------------------------------------------------------------------------
// V transpose: kv16[8192][1536] bf16 (V half at col 768+h*96) ->
//              vT[(b*8+h)*96 + d][1024] bf16
// ---------------------------------------------------------------------------
__global__ __launch_bounds__(256) void trv(
    const unsigned short* __restrict__ kv16, unsigned short* __restrict__ vT)
{
    const int bid = blockIdx.x;       // (b*8+h)*16 + nt
    const int nt = bid & 15, bh = bid >> 4;
    const int b = bh >> 3, h = bh & 7;
    const int n0 = nt * 64;
    const int t = threadIdx.x;

    __shared__ unsigned short tile[64][104];

    for (int i = t; i < 768; i += 256) {
        int r = i / 12, c = i % 12;
        *(uint4*)&tile[r][c * 8] =
            *(const uint4*)&kv16[(size_t)(b * 1024 + n0 + r) * 1536 + 768 + h * 96 + c * 8];
    }
    __syncthreads();

    for (int i = t; i < 768; i += 256) {
        int d = i >> 3, c = i & 7;
        ushort4 lo, hi;
        lo.x = tile[c * 8 + 0][d]; lo.y = tile[c * 8 + 1][d];
        lo.z = tile[c * 8 + 2][d]; lo.w = tile[c * 8 + 3][d];
        hi.x = tile[c * 8 + 4][d]; hi.y = tile[c * 8 + 5][d];
        hi.z = tile[c * 8 + 6][d]; hi.w = tile[c * 8 + 7][d];
        const size_t ob = ((size_t)bh * 96 + d) * 1024 + n0 + c * 8;
        *(ushort4*)&vT[ob]     = lo;
        *(ushort4*)&vT[ob + 4] = hi;
    }
}

// ---------------------------------------------------------------------------
// bf16 MFMA GEMM, NT form: C[M,N] = A[M,K] @ Bt[N,K]^T. (round-6, unchanged)
// MODE 0: bf16 out. MODE 1: fp32 out + bias, split-A (A + Alo).
// ---------------------------------------------------------------------------
template <int MODE>
__global__ __launch_bounds__(256) void mfma_gemm(
    const unsigned short* __restrict__ A,
    const unsigned short* __restrict__ Alo,
    const unsigned short* __restrict__ Bt,
    const float* __restrict__ bias,
    unsigned short* __restrict__ Cb, float* __restrict__ Cf,
    int N, int K)
{
    __shared__ unsigned short As[128 * 32];
    __shared__ unsigned short Bs[128 * 32];
    __shared__ unsigned short Als[MODE == 1 ? 128 * 32 : 8];

    const int tid  = threadIdx.x;
    const int lane = tid & 63, wv = tid >> 6;
    const int bm = blockIdx.y * 128, bn = blockIdx.x * 128;
    const int mcol = lane & 15, quad = lane >> 4;
    const int wr = (wv & 1) * 64, wc = (wv >> 1) * 64;
    const int srow = lane >> 2;
    const int skch = (lane & 3) * 8;

    f32x4 acc[4][4];
#pragma unroll
    for (int i = 0; i < 4; ++i)
#pragma unroll
        for (int j = 0; j < 4; ++j) acc[i][j] = (f32x4){0.f, 0.f, 0.f, 0.f};

    for (int k0 = 0; k0 < K; k0 += 32) {
#pragma unroll
        for (int c = 0; c < 2; ++c) {
            const int s = wv * 2 + c;
            const int row = s * 16 + srow;
            gll16(&A [(size_t)(bm + row) * K + k0 + skch], &As[s * 512]);
            gll16(&Bt[(size_t)(bn + row) * K + k0 + skch], &Bs[s * 512]);
            if (MODE == 1)
                gll16(&Alo[(size_t)(bm + row) * K + k0 + skch], &Als[s * 512]);
        }
        __syncthreads();

        bf16x8 af[4], bfr[4], al[4];
#pragma unroll
        for (int i = 0; i < 4; ++i) {
            af[i]  = *(const bf16x8*)&As[(wr + i * 16 + mcol) * 32 + quad * 8];
            bfr[i] = *(const bf16x8*)&Bs[(wc + i * 16 + mcol) * 32 + quad * 8];
            if (MODE == 1)
                al[i] = *(const bf16x8*)&Als[(wr + i * 16 + mcol) * 32 + quad * 8];
        }
#pragma unroll
        for (int i = 0; i < 4; ++i)
#pragma unroll
            for (int j = 0; j < 4; ++j) {
                acc[i][j] = __builtin_amdgcn_mfma_f32_16x16x32_bf16(af[i], bfr[j], acc[i][j], 0, 0, 0);
                if (MODE == 1)
                    acc[i][j] = __builtin_amdgcn_mfma_f32_16x16x32_bf16(al[i], bfr[j], acc[i][j], 0, 0, 0);
            }
        __syncthreads();
    }

#pragma unroll
    for (int j = 0; j < 4; ++j) {
        const int col = bn + wc + j * 16 + mcol;
        float bs = 0.f;
        if (MODE == 1) bs = bias[col];
#pragma unroll
        for (int i = 0; i < 4; ++i)
#pragma unroll
            for (int rg = 0; rg < 4; ++rg) {
                const int rrow = bm + wr + i * 16 + quad * 4 + rg;
                if (MODE == 0) Cb[(size_t)rrow * N + col] = f2bf(acc[i][j][rg]);
                else           Cf[(size_t)rrow * N + col] = acc[i][j][rg] + bs;
            }
    }
}

// ---------------------------------------------------------------------------
// Attention v5: TQ=16 (no row duplication), register-resident logits+softmax,
// inline threefry (overlaps latency). One block per (b,h,16-row tile);
// 4096 blocks x 256 threads. LDS ~34 KB -> 4 blocks/CU.
// C-layout: row=quad*4+rg, col=(wv*16+nt)*16+mcol. cls cols {0..19} are
// entirely in wave 0 (nt=0 all, nt=1 mcol<4).
// SCALE_ is folded into Wqt, so QK output is already the scaled logit.
// ---------------------------------------------------------------------------
__global__ __launch_bounds__(256, 4) void attn_kernel(
    const unsigned short* __restrict__ qb, const unsigned short* __restrict__ kv16,
    const unsigned short* __restrict__ vT,
    unsigned short* __restrict__ xh, unsigned short* __restrict__ xl)
{
    const int bid  = blockIdx.x;       // b*8*64 + h*64 + tile
    const int tile = bid & 63;
    const int h    = (bid >> 6) & 7;
    const int b    = bid >> 9;
    const int lq0  = tile * TQ;
    const int tid  = threadIdx.x;
    const int lane = tid & 63;
    const int wv   = tid >> 6;
    const int mcol = lane & 15;
    const int quad = lane >> 4;
    const int row0 = quad * 4;          // first of this lane's 4 C-rows

    __shared__ __align__(16) unsigned short sPb[16 * 1032];   // 33 KB
    __shared__ float sM1[4][16], sS1[4][16], sM2[4][16], sS2[4][16];
    __shared__ float sCm[16], sCs[16];

    // ---- QK^T via MFMA: wave wv covers cols [wv*256, wv*256+256) ----
    f32x4 d[16];
    {
        const size_t qrow = ((size_t)(b * NT) + lq0 + mcol) * 768 + h * 96 + quad * 8;
        const bf16x8 qa0 = *(const bf16x8*)&qb[qrow];
        const bf16x8 qa1 = *(const bf16x8*)&qb[qrow + 32];
        const bf16x8 qa2 = *(const bf16x8*)&qb[qrow + 64];
#pragma unroll
        for (int nt = 0; nt < 16; ++nt) {
            const int n0 = (wv * 16 + nt) * 16;
            const size_t krow = ((size_t)(b * NK) + n0 + mcol) * 1536 + h * 96 + quad * 8;
            f32x4 acc = {0.f, 0.f, 0.f, 0.f};
            acc = __builtin_amdgcn_mfma_f32_16x16x32_bf16(qa0, *(const bf16x8*)&kv16[krow],      acc, 0, 0, 0);
            acc = __builtin_amdgcn_mfma_f32_16x16x32_bf16(qa1, *(const bf16x8*)&kv16[krow + 32], acc, 0, 0, 0);
            acc = __builtin_amdgcn_mfma_f32_16x16x32_bf16(qa2, *(const bf16x8*)&kv16[krow + 64], acc, 0, 0, 0);
            d[nt] = acc;
        }
    }

    // ---- threefry mask bits for this lane's 64 (row,col) elements ----
    // bit index i = nt*4+rg -> m0 (i<32) / m1. Rolled nt loop keeps code small.
    uint32_t m0 = 0u, m1 = 0u;
    {
        const uint32_t rowg =
            ((uint32_t)(b * 8 + h) * (uint32_t)L_ + (uint32_t)(lq0 + row0 + CLS_)) * 1024u;
        for (int nt = 0; nt < 16; ++nt) {
            const uint32_t col = (uint32_t)(((wv * 16 + nt) << 4) + mcol);
            uint32_t acc = 0u;
#pragma unroll
            for (int rg = 0; rg < 4; ++rg) {
                uint32_t bits = tf_bits(rowg + 1024u * (uint32_t)rg + col);
                acc |= (bits < MASK_THR ? 1u : 0u) << rg;
            }
            if (nt < 8) m0 |= acc << (nt * 4);
            else        m1 |= acc << ((nt - 8) * 4);
        }
    }

    // ---- patch max (cols >= 20) ----
    float pmax[4] = {-INFINITY, -INFINITY, -INFINITY, -INFINITY};
#pragma unroll
    for (int nt = 0; nt < 16; ++nt) {
        if (wv == 0 && nt == 0) continue;               // cols 0..15: all cls
        bool clslane = (wv == 0 && nt == 1 && mcol < 4); // cols 16..19
#pragma unroll
        for (int rg = 0; rg < 4; ++rg)
            if (!clslane) pmax[rg] = fmaxf(pmax[rg], d[nt][rg]);
    }
#pragma unroll
    for (int rg = 0; rg < 4; ++rg)
#pragma unroll
        for (int m = 1; m <= 8; m <<= 1) pmax[rg] = fmaxf(pmax[rg], __shfl_xor(pmax[rg], m));
    if (mcol == 0)
#pragma unroll
        for (int rg = 0; rg < 4; ++rg) sM1[wv][row0 + rg] = pmax[rg];

    // ---- cls max (wave 0 only; cols 0..19) ----
    if (wv == 0) {
        float cmax[4];
#pragma unroll
        for (int rg = 0; rg < 4; ++rg) {
            float c = d[0][rg];
            if (mcol < 4) c = fmaxf(c, d[1][rg]);
            cmax[rg] = c;
        }
#pragma unroll
        for (int rg = 0; rg < 4; ++rg)
#pragma unroll
            for (int m = 1; m <= 8; m <<= 1) cmax[rg] = fmaxf(cmax[rg], __shfl_xor(cmax[rg], m));
        if (mcol == 0)
#pragma unroll
            for (int rg = 0; rg < 4; ++rg) sCm[row0 + rg] = cmax[rg];
    }
    __syncthreads();

    float pm[4], cm[4];
#pragma unroll
    for (int rg = 0; rg < 4; ++rg) {
        const int rr = row0 + rg;
        pm[rg] = fmaxf(fmaxf(sM1[0][rr], sM1[1][rr]), fmaxf(sM1[2][rr], sM1[3][rr]));
        cm[rg] = sCm[rr];
    }

    // ---- exp pass (in regs) + partial sums ----
    float ps[4] = {0.f, 0.f, 0.f, 0.f}, cs[4] = {0.f, 0.f, 0.f, 0.f};
#pragma unroll
    for (int nt = 0; nt < 16; ++nt) {
        const bool c_all = (wv == 0 && nt == 0);
        const bool c_few = (wv == 0 && nt == 1);
#pragma unroll
        for (int rg = 0; rg < 4; ++rg) {
            const bool iscls = c_all || (c_few && mcol < 4);
            float e = __expf(d[nt][rg] - (iscls ? cm[rg] : pm[rg]));
            d[nt][rg] = e;
            if (iscls) cs[rg] += e; else ps[rg] += e;
        }
    }
#pragma unroll
    for (int rg = 0; rg < 4; ++rg)
#pragma unroll
        for (int m = 1; m <= 8; m <<= 1) ps[rg] += __shfl_xor(ps[rg], m);
    if (mcol == 0)
#pragma unroll
        for (int rg = 0; rg < 4; ++rg) sS1[wv][row0 + rg] = ps[rg];
    if (wv == 0) {
#pragma unroll
        for (int rg = 0; rg < 4; ++rg)
#pragma unroll
            for (int m = 1; m <= 8; m <<= 1) cs[rg] += __shfl_xor(cs[rg], m);
        if (mcol == 0)
#pragma unroll
            for (int rg = 0; rg < 4; ++rg) sCs[row0 + rg] = cs[rg];
    }
    __syncthreads();

    float ips[4], ics[4];
#pragma unroll
    for (int rg = 0; rg < 4; ++rg) {
        const int rr = row0 + rg;
        ips[rg] = 1.f / (sS1[0][rr] + sS1[1][rr] + sS1[2][rr] + sS1[3][rr]);
        ics[rg] = 1.f / sCs[rr];
    }

    // ---- probs + mask -> -1e30 (exp2 later underflows to exact 0) ----
#pragma unroll
    for (int nt = 0; nt < 16; ++nt) {
        const bool c_all = (wv == 0 && nt == 0);
        const bool c_few = (wv == 0 && nt == 1);
#pragma unroll
        for (int rg = 0; rg < 4; ++rg) {
            const bool iscls = c_all || (c_few && mcol < 4);
            float p = d[nt][rg] * (iscls ? ics[rg] : ips[rg]);
            const int i = nt * 4 + rg;
            const uint32_t bit = (i < 32) ? (m0 >> i) : (m1 >> (i - 32));
            d[nt][rg] = (bit & 1u) ? -1e30f : p;
        }
    }

    // ---- second softmax: max ----
    float mx2[4];
#pragma unroll
    for (int rg = 0; rg < 4; ++rg) mx2[rg] = d[0][rg];
#pragma unroll
    for (int nt = 1; nt < 16; ++nt)
#pragma unroll
        for (int rg = 0; rg < 4; ++rg) mx2[rg] = fmaxf(mx2[rg], d[nt][rg]);
#pragma unroll
    for (int rg = 0; rg < 4; ++rg)
#pragma unroll
        for (int m = 1; m <= 8; m <<= 1) mx2[rg] = fmaxf(mx2[rg], __shfl_xor(mx2[rg], m));
    if (mcol == 0)
#pragma unroll
        for (int rg = 0; rg < 4; ++rg) sM2[wv][row0 + rg] = mx2[rg];
    __syncthreads();

    float m2[4];
#pragma unroll
    for (int rg = 0; rg < 4; ++rg) {
        const int rr = row0 + rg;
        m2[rg] = fmaxf(fmaxf(sM2[0][rr], sM2[1][rr]), fmaxf(sM2[2][rr], sM2[3][rr]));
    }

    // ---- exp2 -> bf16 sPb (unnormalized) + s2 partials ----
    float s2[4] = {0.f, 0.f, 0.f, 0.f};
#pragma unroll
    for (int nt = 0; nt < 16; ++nt) {
        const int col = (wv * 16 + nt) * 16 + mcol;
#pragma unroll
        for (int rg = 0; rg < 4; ++rg) {
            float e2 = __expf(d[nt][rg] - m2[rg]);
            s2[rg] += e2;
            sPb[(row0 + rg) * 1032 + col] = f2bf(e2);
        }
    }
#pragma unroll
    for (int rg = 0; rg < 4; ++rg)
#pragma unroll
        for (int m = 1; m <= 8; m <<= 1) s2[rg] += __shfl_xor(s2[rg], m);
    if (mcol == 0)
#pragma unroll
        for (int rg = 0; rg < 4; ++rg) sS2[wv][row0 + rg] = s2[rg];
    __syncthreads();

    // ---- PV via MFMA: wave wv owns d-tiles {wv, wv+4 (if <6)} ----
    {
        const int t0 = wv, t1 = wv + 4;
        const size_t vbase = ((size_t)(b * 8 + h)) * 96 * 1024;
        f32x4 a0 = {0.f, 0.f, 0.f, 0.f};
        f32x4 a1 = {0.f, 0.f, 0.f, 0.f};
#pragma unroll 4
        for (int k0 = 0; k0 < 1024; k0 += 32) {
            const bf16x8 pa = *(const bf16x8*)&sPb[mcol * 1032 + k0 + quad * 8];
            const size_t v0 = vbase + (size_t)(t0 * 16 + mcol) * 1024 + k0 + quad * 8;
            a0 = __builtin_amdgcn_mfma_f32_16x16x32_bf16(pa, *(const bf16x8*)&vT[v0], a0, 0, 0, 0);
            if (t1 < 6) {
                const size_t v1 = vbase + (size_t)(t1 * 16 + mcol) * 1024 + k0 + quad * 8;
                a1 = __builtin_amdgcn_mfma_f32_16x16x32_bf16(pa, *(const bf16x8*)&vT[v1], a1, 0, 0, 0);
            }
        }

        float inv[4];
#pragma unroll
        for (int rg = 0; rg < 4; ++rg) {
            const int rr = row0 + rg;
            inv[rg] = 1.f / (sS2[0][rr] + sS2[1][rr] + sS2[2][rr] + sS2[3][rr]);
        }
#pragma unroll
        for (int rg = 0; rg < 4; ++rg) {
            const size_t ob = ((size_t)(b * NT) + lq0 + row0 + rg) * 768 + h * 96;
            {
                float val = a0[rg] * inv[rg];
                unsigned short hb = f2bf(val);
                xh[ob + t0 * 16 + mcol] = hb;
                xl[ob + t0 * 16 + mcol] = f2bf(val - __uint_as_float((uint32_t)hb << 16));
            }
            if (t1 < 6) {
                float val = a1[rg] * inv[rg];
                unsigned short hb = f2bf(val);
                xh[ob + t1 * 16 + mcol] = hb;
                xl[ob + t1 * 16 + mcol] = f2bf(val - __uint_as_float((uint32_t)hb << 16));
            }
        }
    }
}

// ---------------------------------------------------------------------------
extern "C" void kernel_launch(void* const* d_in, const int* in_sizes, int n_in,
                              void* d_out, int out_size, void* d_ws, size_t ws_size,
                              hipStream_t stream)
{
    const float* in_q   = (const float*)d_in[0];
    const float* in_k   = (const float*)d_in[1];
    const float* Wq     = (const float*)d_in[2];
    const float* Wkv    = (const float*)d_in[3];
    // d_in[4] = Wcls — unused (cls query rows are dropped by the reference)
    const float* Wproj  = (const float*)d_in[5];
    const float* bproj  = (const float*)d_in[6];
    float* out = (float*)d_out;

    // workspace layout (bf16 units)
    unsigned short* ws16 = (unsigned short*)d_ws;
    unsigned short* Aq   = ws16;                  // 6291456
    unsigned short* Ak   = Aq   + 6291456;        // 6291456
    unsigned short* qb   = Ak   + 6291456;        // 6291456
    unsigned short* kv16 = qb   + 6291456;        // 12582912
    unsigned short* vT   = kv16 + 12582912;       // 6291456
    unsigned short* Wqt  = vT   + 6291456;        // 589824
    unsigned short* Wkvt = Wqt  + 589824;         // 1179648
    unsigned short* Wpt  = Wkvt + 1179648;        // 589824
    unsigned short* xh   = Aq;                    // reuse (dead after gemm_q)
    unsigned short* xl   = Ak;                    // reuse (dead after gemm_kv)

    dim3 blk(256);

    conv_bf16<<<6144, blk, 0, stream>>>(in_q, Aq, 1572864);
    conv_bf16<<<6144, blk, 0, stream>>>(in_k, Ak, 1572864);
    trw_bf16<<<dim3(24, 24), blk, 0, stream>>>(Wq,    Wqt,  768,  SCALE_);
    trw_bf16<<<dim3(48, 24), blk, 0, stream>>>(Wkv,   Wkvt, 1536, 1.f);
    trw_bf16<<<dim3(24, 24), blk, 0, stream>>>(Wproj, Wpt,  768,  1.f);

    mfma_gemm<0><<<dim3(6, 64), blk, 0, stream>>>(
        Aq, nullptr, Wqt, nullptr, qb, nullptr, 768, 768);

    mfma_gemm<0><<<dim3(12, 64), blk, 0, stream>>>(
        Ak, nullptr, Wkvt, nullptr, kv16, nullptr, 1536, 768);

    trv<<<1024, blk, 0, stream>>>(kv16, vT);

    attn_kernel<<<4096, blk, 0, stream>>>(qb, kv16, vT, xh, xl);

    mfma_gemm<1><<<dim3(6, 64), blk, 0, stream>>>(
        xh, xl, Wpt, bproj, nullptr, out, 768, 768);
}